// Round 1
// baseline (572.854 us; speedup 1.0000x reference)
//
#include <hip/hip_runtime.h>

#define N_NODES 100000
#define N_EDGES 1000000
#define D_IN    256
#define D_OUT   64

// ---------------------------------------------------------------------------
// GEMM: hidden[N, 64] = x[N, 256] @ w[256, 64]
// One wave per output row; lane = output column. x row staged in LDS,
// w streams through L1 (64 KB total, fully cached after first blocks).
// ---------------------------------------------------------------------------
__global__ __launch_bounds__(256) void gemm_kernel(
    const float* __restrict__ x, const float* __restrict__ w,
    float* __restrict__ hidden)
{
    __shared__ float xs[4][D_IN];
    const int rowBase = blockIdx.x * 4;
    const int wave = threadIdx.x >> 6;
    const int lane = threadIdx.x & 63;

    // Cooperative load of 4 rows (4*256 floats) with float4: 256 threads x 1 float4.
    {
        int idx = threadIdx.x * 4;      // 0..1023
        int rr  = idx >> 8;             // row within tile
        int cc  = idx & 255;            // col within row
        int gr  = rowBase + rr;
        if (gr < N_NODES) {
            *(float4*)&xs[rr][cc] = *(const float4*)(x + (size_t)gr * D_IN + cc);
        }
    }
    __syncthreads();

    const int r = rowBase + wave;
    if (r < N_NODES) {
        float acc = 0.f;
#pragma unroll 8
        for (int k = 0; k < D_IN; ++k) {
            acc += xs[wave][k] * w[k * D_OUT + lane];
        }
        hidden[(size_t)r * D_OUT + lane] = acc;
    }
}

// ---------------------------------------------------------------------------
// Edge kernel: for each edge e, out[row[e]] += adj[e] * hidden[col[e]]
// One wave per edge; lane = feature dim (64 == D_OUT, perfectly coalesced).
// ---------------------------------------------------------------------------
__global__ __launch_bounds__(256) void edge_kernel(
    const float* __restrict__ hidden, const float* __restrict__ adj,
    const int* __restrict__ row, const int* __restrict__ col,
    float* __restrict__ out)
{
    const int e = blockIdx.x * 4 + (threadIdx.x >> 6);
    const int lane = threadIdx.x & 63;
    if (e >= N_EDGES) return;
    const int r = row[e];
    const int c = col[e];
    const float v = adj[e];
    const float h = hidden[(size_t)c * D_OUT + lane];
    atomicAdd(&out[(size_t)r * D_OUT + lane], v * h);
}

// ---------------------------------------------------------------------------
// PReLU: out = out > 0 ? out : a * out   (in-place, vectorized)
// ---------------------------------------------------------------------------
__global__ __launch_bounds__(256) void prelu_kernel(
    float* __restrict__ out, const float* __restrict__ prelu_a, int n4)
{
    const float a = prelu_a[0];
    int i = blockIdx.x * blockDim.x + threadIdx.x;
    int stride = gridDim.x * blockDim.x;
    for (; i < n4; i += stride) {
        float4 v = ((float4*)out)[i];
        v.x = v.x > 0.f ? v.x : a * v.x;
        v.y = v.y > 0.f ? v.y : a * v.y;
        v.z = v.z > 0.f ? v.z : a * v.z;
        v.w = v.w > 0.f ? v.w : a * v.w;
        ((float4*)out)[i] = v;
    }
}

extern "C" void kernel_launch(void* const* d_in, const int* in_sizes, int n_in,
                              void* d_out, int out_size, void* d_ws, size_t ws_size,
                              hipStream_t stream)
{
    const float* x       = (const float*)d_in[0];
    const float* w       = (const float*)d_in[1];
    const float* adj     = (const float*)d_in[2];
    const float* prelu_a = (const float*)d_in[3];
    const int*   row     = (const int*)d_in[4];
    const int*   col     = (const int*)d_in[5];
    float* out    = (float*)d_out;
    float* hidden = (float*)d_ws;   // 100000*64*4 = 25.6 MB scratch

    // 1. hidden = x @ w
    gemm_kernel<<<(N_NODES + 3) / 4, 256, 0, stream>>>(x, w, hidden);

    // 2. zero accumulator (d_out is poisoned 0xAA before every launch)
    hipMemsetAsync(d_out, 0, (size_t)out_size * sizeof(float), stream);

    // 3. scatter-add messages
    edge_kernel<<<(N_EDGES + 3) / 4, 256, 0, stream>>>(hidden, adj, row, col, out);

    // 4. PReLU in place
    int n4 = out_size / 4;
    int blocks = (n4 + 255) / 256;
    if (blocks > 4096) blocks = 4096;
    prelu_kernel<<<blocks, 256, 0, stream>>>(out, prelu_a, n4);
}

// Round 2
// 355.118 us; speedup vs baseline: 1.6131x; 1.6131x over previous
//
#include <hip/hip_runtime.h>

#define N_NODES 100000
#define N_EDGES 1000000
#define D_IN    256
#define D_OUT   64

typedef __attribute__((ext_vector_type(8))) short short8;
typedef __attribute__((ext_vector_type(4))) float f32x4;

__device__ __forceinline__ unsigned short f2bf(float f) {
    // fp32 -> bf16 round-to-nearest-even
    unsigned int u = __float_as_uint(f);
    u = (u + 0x7fffu + ((u >> 16) & 1u)) >> 16;
    return (unsigned short)u;
}

// ---------------------------------------------------------------------------
// GEMM: hidden[100000,64] = x[100000,256] @ w[256,64] via bf16 MFMA 16x16x32.
// Per wave: 16-row tile, full K=256 (8 chunks), all 4 col-tiles (D_OUT=64).
// B fragments register-resident (loaded once from LDS-staged bf16 w^T).
// A: coalesced float4 loads + in-reg RNE convert. Memory-bound on x (102 MB).
// ---------------------------------------------------------------------------
__global__ __launch_bounds__(256) void gemm_kernel(
    const float* __restrict__ x, const float* __restrict__ w,
    float* __restrict__ hidden, int numTiles)
{
    // w^T in LDS as bf16, padded row (+8) to break bank aliasing on b128 reads
    __shared__ unsigned short wT[64][264];
    const int t = threadIdx.x;

    for (int i = 0; i < 64; ++i) {
        int idx = t + i * 256;            // 0..16383
        int k = idx >> 6, n = idx & 63;   // w[k][n], n contiguous -> coalesced
        wT[n][k] = f2bf(w[idx]);
    }
    __syncthreads();

    const int lane = t & 63;
    const int wid  = t >> 6;
    const int n16  = lane & 15;
    const int quad = lane >> 4;

    // B fragments: B[n = lane&15 (+16*ct)][k = kk*32 + quad*8 + j]
    short8 bfrag[4][8];
#pragma unroll
    for (int ct = 0; ct < 4; ++ct) {
        int n = ct * 16 + n16;
#pragma unroll
        for (int kk = 0; kk < 8; ++kk) {
            bfrag[ct][kk] = *(const short8*)&wT[n][kk * 32 + quad * 8];
        }
    }

    const int waveGid   = blockIdx.x * 4 + wid;
    const int waveCount = gridDim.x * 4;

    for (int tile = waveGid; tile < numTiles; tile += waveCount) {
        const int r0 = tile * 16;
        const float* xrow = x + (size_t)(r0 + n16) * D_IN + quad * 8;

        // A fragments: A[m = lane&15][k = kk*32 + quad*8 + j]
        short8 afrag[8];
#pragma unroll
        for (int kk = 0; kk < 8; ++kk) {
            float4 lo = *(const float4*)(xrow + kk * 32);
            float4 hi = *(const float4*)(xrow + kk * 32 + 4);
            short8 a;
            a[0] = (short)f2bf(lo.x); a[1] = (short)f2bf(lo.y);
            a[2] = (short)f2bf(lo.z); a[3] = (short)f2bf(lo.w);
            a[4] = (short)f2bf(hi.x); a[5] = (short)f2bf(hi.y);
            a[6] = (short)f2bf(hi.z); a[7] = (short)f2bf(hi.w);
            afrag[kk] = a;
        }

        f32x4 acc[4] = {{0.f,0.f,0.f,0.f},{0.f,0.f,0.f,0.f},
                        {0.f,0.f,0.f,0.f},{0.f,0.f,0.f,0.f}};
#pragma unroll
        for (int ct = 0; ct < 4; ++ct)
#pragma unroll
            for (int kk = 0; kk < 8; ++kk)
                acc[ct] = __builtin_amdgcn_mfma_f32_16x16x32_bf16(
                    afrag[kk], bfrag[ct][kk], acc[ct], 0, 0, 0);

        // C/D layout: col = lane&15, row = quad*4 + reg  [m89-verified]
#pragma unroll
        for (int ct = 0; ct < 4; ++ct)
#pragma unroll
            for (int reg = 0; reg < 4; ++reg)
                hidden[(size_t)(r0 + quad * 4 + reg) * D_OUT + ct * 16 + n16]
                    = acc[ct][reg];
    }
}

// ---------------------------------------------------------------------------
// CSR build: histogram -> exclusive scan -> scatter (int atomics only)
// ---------------------------------------------------------------------------
__global__ __launch_bounds__(256) void hist_kernel(
    const int* __restrict__ row, int* __restrict__ deg)
{
    int e = blockIdx.x * 256 + threadIdx.x;
    if (e < N_EDGES) atomicAdd(&deg[row[e]], 1);
}

// blocks of 1024 elems (256 thr x 4): local exclusive scan + block total
__global__ __launch_bounds__(256) void scan1_kernel(
    const int* __restrict__ deg, int* __restrict__ starts,
    int* __restrict__ blockTot)
{
    __shared__ int sums[256];
    const int b = blockIdx.x, t = threadIdx.x;
    const int base = b * 1024 + t * 4;

    int4 v = make_int4(0, 0, 0, 0);
    if (base + 3 < N_NODES) {
        v = *(const int4*)(deg + base);
    } else {
        if (base + 0 < N_NODES) v.x = deg[base + 0];
        if (base + 1 < N_NODES) v.y = deg[base + 1];
        if (base + 2 < N_NODES) v.z = deg[base + 2];
        if (base + 3 < N_NODES) v.w = deg[base + 3];
    }
    int s = v.x + v.y + v.z + v.w;
    sums[t] = s;
    __syncthreads();
    for (int off = 1; off < 256; off <<= 1) {
        int tmp = (t >= off) ? sums[t - off] : 0;
        __syncthreads();
        sums[t] += tmp;
        __syncthreads();
    }
    int run = sums[t] - s;                 // exclusive prefix of this thread
    if (t == 255) blockTot[b] = sums[255];
    if (base + 0 < N_NODES) starts[base + 0] = run; run += v.x;
    if (base + 1 < N_NODES) starts[base + 1] = run; run += v.y;
    if (base + 2 < N_NODES) starts[base + 2] = run; run += v.z;
    if (base + 3 < N_NODES) starts[base + 3] = run;
}

// add block offsets; also produce cursor copy and starts[N] sentinel
__global__ __launch_bounds__(256) void scan2_kernel(
    int* __restrict__ starts, int* __restrict__ cursor,
    const int* __restrict__ blockTot)
{
    const int b = blockIdx.x, t = threadIdx.x;
    int offset = 0;
    for (int i = 0; i < b; ++i) offset += blockTot[i];  // uniform scalar loop
    const int base = b * 1024 + t * 4;
#pragma unroll
    for (int j = 0; j < 4; ++j) {
        int idx = base + j;
        if (idx < N_NODES) {
            int s = starts[idx] + offset;
            starts[idx] = s;
            cursor[idx] = s;
        }
    }
    if (b == 0 && t == 0) starts[N_NODES] = N_EDGES;
}

__global__ __launch_bounds__(256) void scatter_kernel(
    const int* __restrict__ row, const int* __restrict__ col,
    const float* __restrict__ adj, int* __restrict__ cursor,
    int2* __restrict__ sorted)
{
    int e = blockIdx.x * 256 + threadIdx.x;
    if (e >= N_EDGES) return;
    int r = row[e];
    int pos = atomicAdd(&cursor[r], 1);
    sorted[pos] = make_int2(col[e], __float_as_int(adj[e]));
}

// ---------------------------------------------------------------------------
// Aggregate: one wave per node, lane = feature. No float atomics.
// PReLU fused into epilogue; writes every node (no out-memset needed).
// ---------------------------------------------------------------------------
__global__ __launch_bounds__(256) void agg_kernel(
    const float* __restrict__ hidden, const int* __restrict__ starts,
    const int2* __restrict__ sorted, const float* __restrict__ prelu_a,
    float* __restrict__ out)
{
    const int wid  = __builtin_amdgcn_readfirstlane(threadIdx.x >> 6);
    const int lane = threadIdx.x & 63;
    const int node = blockIdx.x * 4 + wid;

    const int e0 = starts[node];
    const int e1 = starts[node + 1];

    float acc = 0.f;
    for (int e = e0; e < e1; ++e) {
        int2 cv = sorted[e];                       // wave-uniform -> s_load
        acc += __int_as_float(cv.y) * hidden[(size_t)cv.x * D_OUT + lane];
    }
    const float a = prelu_a[0];
    out[(size_t)node * D_OUT + lane] = acc > 0.f ? acc : a * acc;
}

// ---------------------------------------------------------------------------
extern "C" void kernel_launch(void* const* d_in, const int* in_sizes, int n_in,
                              void* d_out, int out_size, void* d_ws, size_t ws_size,
                              hipStream_t stream)
{
    const float* x       = (const float*)d_in[0];
    const float* w       = (const float*)d_in[1];
    const float* adj     = (const float*)d_in[2];
    const float* prelu_a = (const float*)d_in[3];
    const int*   row     = (const int*)d_in[4];
    const int*   col     = (const int*)d_in[5];
    float* out = (float*)d_out;

    // workspace layout (all 16B-aligned)
    char* ws = (char*)d_ws;
    float* hidden  = (float*)(ws);                    // 25,600,000 B
    int*   deg     = (int*)  (ws + 25600000);         //    400,000 B
    int*   starts  = (int*)  (ws + 26000000);         //    400,004 B
    int*   cursor  = (int*)  (ws + 26400016);         //    400,000 B
    int*   blockTot= (int*)  (ws + 26800016);         //        392 B
    int2*  sorted  = (int2*) (ws + 26801024);         //  8,000,000 B

    const int nScanBlocks = (N_NODES + 1023) / 1024;  // 98

    // GEMM: 512 blocks * 4 waves = 2048 waves, ~3 tiles each
    gemm_kernel<<<512, 256, 0, stream>>>(x, w, hidden, (N_NODES + 15) / 16);

    // CSR build
    hipMemsetAsync(deg, 0, N_NODES * sizeof(int), stream);
    hist_kernel<<<(N_EDGES + 255) / 256, 256, 0, stream>>>(row, deg);
    scan1_kernel<<<nScanBlocks, 256, 0, stream>>>(deg, starts, blockTot);
    scan2_kernel<<<nScanBlocks, 256, 0, stream>>>(starts, cursor, blockTot);
    scatter_kernel<<<(N_EDGES + 255) / 256, 256, 0, stream>>>(row, col, adj, cursor, sorted);

    // node-parallel aggregation + fused PReLU
    agg_kernel<<<N_NODES / 4, 256, 0, stream>>>(hidden, starts, sorted, prelu_a, out);
}